// Round 1
// baseline (1987.786 us; speedup 1.0000x reference)
//
#include <hip/hip_runtime.h>
#include <math.h>

// CurvatureLoss: three brute-force KNN passes + curvature gathers + scalar loss.
// B=2, N=8192, points [B,N,3] fp32.

constexpr int TILE = 512;   // ref points staged per LDS tile
constexpr int QPB  = 64;    // queries per block
constexpr int CPQ  = 4;     // chunk-threads per query
constexpr int BLOCK = QPB * CPQ; // 256
constexpr float RADIUS2 = 2.5f;  // threshold on squared distance

__device__ __forceinline__ float sq3(float x, float y, float z) {
    return fmaf(x, x, fmaf(y, y, z * z));
}
__device__ __forceinline__ float dot3(float ax, float ay, float az,
                                      float bx, float by, float bz) {
    return fmaf(ax, bx, fmaf(ay, by, az * bz));
}
// stable top-k ordering: ascending dist, ties -> ascending index (matches jax.lax.top_k)
__device__ __forceinline__ bool lex_less(float d1, int i1, float d2, int i2) {
    return (d1 < d2) || (d1 == d2 && i1 < i2);
}

// MODE 0: curv2   = curvature(pc_target)            q=ref=gather=pc_target
// MODE 1: moved   = curvature(pc_source, warped)    q=ref=pc_source, gather=src+flow
// MODE 2: interp + loss                              q=warped(src+flow), ref=pc_target
template <int K, int MODE>
__global__ __launch_bounds__(BLOCK)
void knn_kernel(const float* __restrict__ qpts,
                const float* __restrict__ flow,
                const float* __restrict__ refpts,
                const float* __restrict__ curv2,
                const float* __restrict__ moved,
                float* __restrict__ out,
                int N, int bpb, float invB)
{
    __shared__ float4 spt[TILE];
    __shared__ float  smd[QPB][CPQ][K];
    __shared__ int    smi[QPB][CPQ][K];
    __shared__ float  lsum;

    const int tid = threadIdx.x;
    const int ql  = tid >> 2;   // query within block
    const int c   = tid & 3;    // chunk id
    const int b   = blockIdx.x / bpb;
    const int qi  = (blockIdx.x % bpb) * QPB + ql;
    const size_t bbase = (size_t)b * N * 3;

    const float* rb = refpts + bbase;
    const float* fb = (flow != nullptr) ? (flow + bbase) : nullptr;

    // query point
    float qx = qpts[bbase + (size_t)qi * 3 + 0];
    float qy = qpts[bbase + (size_t)qi * 3 + 1];
    float qz = qpts[bbase + (size_t)qi * 3 + 2];
    if (MODE == 2) {  // query = warped = src + flow
        qx += fb[(size_t)qi * 3 + 0];
        qy += fb[(size_t)qi * 3 + 1];
        qz += fb[(size_t)qi * 3 + 2];
    }
    const float qq = sq3(qx, qy, qz);

    float bd[K]; int bi[K];
#pragma unroll
    for (int k = 0; k < K; ++k) { bd[k] = INFINITY; bi[k] = 0x7FFFFFFF; }

    for (int t0 = 0; t0 < N; t0 += TILE) {
        __syncthreads();
#pragma unroll
        for (int j = tid; j < TILE; j += BLOCK) {
            float x = rb[(size_t)(t0 + j) * 3 + 0];
            float y = rb[(size_t)(t0 + j) * 3 + 1];
            float z = rb[(size_t)(t0 + j) * 3 + 2];
            spt[j] = make_float4(x, y, z, sq3(x, y, z));
        }
        __syncthreads();
#pragma unroll 4
        for (int i = 0; i < TILE / CPQ; ++i) {
            int j = (i << 2) | c;          // interleaved: 4 chunk threads hit 4 banks
            float4 p = spt[j];
            float d = (qq + p.w) - 2.0f * dot3(qx, qy, qz, p.x, p.y, p.z);
            int gj = t0 + j;
            if (lex_less(d, gj, bd[K - 1], bi[K - 1])) {
                bd[K - 1] = d; bi[K - 1] = gj;
                // one bubble pass restores sortedness; all indices compile-time
#pragma unroll
                for (int p2 = K - 1; p2 > 0; --p2) {
                    if (lex_less(bd[p2], bi[p2], bd[p2 - 1], bi[p2 - 1])) {
                        float td = bd[p2]; bd[p2] = bd[p2 - 1]; bd[p2 - 1] = td;
                        int ti = bi[p2];  bi[p2] = bi[p2 - 1]; bi[p2 - 1] = ti;
                    }
                }
            }
        }
    }

#pragma unroll
    for (int k = 0; k < K; ++k) { smd[ql][c][k] = bd[k]; smi[ql][c][k] = bi[k]; }
    if (MODE == 2 && tid == 0) lsum = 0.0f;
    __syncthreads();

    if (c == 0) {
        // stable 4-way merge of sorted per-chunk lists (ptr_c <= k <= K-1: no OOB)
        int p0 = 0, p1 = 0, p2 = 0, p3 = 0;
        float fd[K]; int fi[K];
#pragma unroll
        for (int k = 0; k < K; ++k) {
            float d0 = smd[ql][0][p0]; int i0 = smi[ql][0][p0];
            float d1 = smd[ql][1][p1]; int i1 = smi[ql][1][p1];
            float d2 = smd[ql][2][p2]; int i2 = smi[ql][2][p2];
            float d3 = smd[ql][3][p3]; int i3 = smi[ql][3][p3];
            float bdm = d0; int bim = i0; int bc = 0;
            if (lex_less(d1, i1, bdm, bim)) { bdm = d1; bim = i1; bc = 1; }
            if (lex_less(d2, i2, bdm, bim)) { bdm = d2; bim = i2; bc = 2; }
            if (lex_less(d3, i3, bdm, bim)) { bdm = d3; bim = i3; bc = 3; }
            fd[k] = bdm; fi[k] = bim;
            p0 += (bc == 0); p1 += (bc == 1); p2 += (bc == 2); p3 += (bc == 3);
        }

        if (MODE == 0) {
            float gx = 0.f, gy = 0.f, gz = 0.f;
#pragma unroll
            for (int k = 0; k < K; ++k) {
                int j = (fd[k] > RADIUS2) ? fi[0] : fi[k];
                gx += rb[(size_t)j * 3 + 0] - qx;
                gy += rb[(size_t)j * 3 + 1] - qy;
                gz += rb[(size_t)j * 3 + 2] - qz;
            }
            out[bbase + (size_t)qi * 3 + 0] = gx / 9.0f;
            out[bbase + (size_t)qi * 3 + 1] = gy / 9.0f;
            out[bbase + (size_t)qi * 3 + 2] = gz / 9.0f;
        } else if (MODE == 1) {
            // subtract warped[i], gather warped[j] = src[j] + flow[j]
            float wxi = qx + fb[(size_t)qi * 3 + 0];
            float wyi = qy + fb[(size_t)qi * 3 + 1];
            float wzi = qz + fb[(size_t)qi * 3 + 2];
            float gx = 0.f, gy = 0.f, gz = 0.f;
#pragma unroll
            for (int k = 0; k < K; ++k) {
                int j = (fd[k] > RADIUS2) ? fi[0] : fi[k];
                gx += (rb[(size_t)j * 3 + 0] + fb[(size_t)j * 3 + 0]) - wxi;
                gy += (rb[(size_t)j * 3 + 1] + fb[(size_t)j * 3 + 1]) - wyi;
                gz += (rb[(size_t)j * 3 + 2] + fb[(size_t)j * 3 + 2]) - wzi;
            }
            out[bbase + (size_t)qi * 3 + 0] = gx / 9.0f;
            out[bbase + (size_t)qi * 3 + 1] = gy / 9.0f;
            out[bbase + (size_t)qi * 3 + 2] = gz / 9.0f;
        } else {
            // interp: weights from unmasked sorted dists, gather curv2 at masked idx
            float w[K]; float wsum = 0.f;
#pragma unroll
            for (int k = 0; k < K; ++k) { w[k] = 1.0f / (fd[k] + 1e-8f); wsum += w[k]; }
            float ix = 0.f, iy = 0.f, iz = 0.f;
#pragma unroll
            for (int k = 0; k < K; ++k) {
                int j = (fd[k] > RADIUS2) ? fi[0] : fi[k];
                float wn = w[k] / wsum;
                ix += wn * curv2[bbase + (size_t)j * 3 + 0];
                iy += wn * curv2[bbase + (size_t)j * 3 + 1];
                iz += wn * curv2[bbase + (size_t)j * 3 + 2];
            }
            float dx = ix - moved[bbase + (size_t)qi * 3 + 0];
            float dy = iy - moved[bbase + (size_t)qi * 3 + 1];
            float dz = iz - moved[bbase + (size_t)qi * 3 + 2];
            float sqv = fmaf(dx, dx, fmaf(dy, dy, dz * dz));
            atomicAdd(&lsum, sqv);
        }
    }

    if (MODE == 2) {
        __syncthreads();
        if (tid == 0) atomicAdd(out, lsum * invB);
    }
}

extern "C" void kernel_launch(void* const* d_in, const int* in_sizes, int n_in,
                              void* d_out, int out_size, void* d_ws, size_t ws_size,
                              hipStream_t stream) {
    const float* src  = (const float*)d_in[0];  // pc_source [B,N,3]
    const float* tgt  = (const float*)d_in[1];  // pc_target [B,N,3]
    const float* flow = (const float*)d_in[2];  // pred_flow [B,N,3]
    float* out = (float*)d_out;

    const int B = 2;
    const int N = in_sizes[0] / (B * 3);   // 8192
    const int bpb = N / QPB;               // blocks per batch
    const int grid = B * bpb;

    float* curv2 = (float*)d_ws;                       // [B,N,3]
    float* moved = curv2 + (size_t)B * N * 3;          // [B,N,3]

    hipMemsetAsync(d_out, 0, sizeof(float), stream);

    // curv2 = curvature(pc_target)
    knn_kernel<10, 0><<<grid, BLOCK, 0, stream>>>(tgt, nullptr, tgt, nullptr, nullptr,
                                                  curv2, N, bpb, 0.f);
    // moved = curvature(pc_source, warped)
    knn_kernel<10, 1><<<grid, BLOCK, 0, stream>>>(src, flow, src, nullptr, nullptr,
                                                  moved, N, bpb, 0.f);
    // inter + loss
    knn_kernel<5, 2><<<grid, BLOCK, 0, stream>>>(src, flow, tgt, curv2, moved,
                                                 out, N, bpb, 1.0f / B);
}

// Round 2
// 632.498 us; speedup vs baseline: 3.1428x; 3.1428x over previous
//
#include <hip/hip_runtime.h>
#include <math.h>

// CurvatureLoss: brute-force KNN passes + curvature gathers + scalar loss.
// B=2, N=8192, points [B,N,3] fp32. All data L2-resident; VALU/latency-bound.

constexpr int TILE  = 512;   // ref points staged per LDS tile
constexpr int BLOCK = 256;
constexpr float RADIUS2 = 2.5f;

__device__ __forceinline__ float sq3(float x, float y, float z) {
    return fmaf(x, x, fmaf(y, y, z * z));
}
__device__ __forceinline__ float dot3(float ax, float ay, float az,
                                      float bx, float by, float bz) {
    return fmaf(ax, bx, fmaf(ay, by, az * bz));
}
// stable ordering: ascending dist, ties -> ascending index (matches jax.lax.top_k)
__device__ __forceinline__ bool lex_less(float d1, int i1, float d2, int i2) {
    return (d1 < d2) || (d1 == d2 && i1 < i2);
}

// KIND 0: fused curvature passes (mode derived from blockIdx):
//   mode 0: q=ref=gather=tgt           -> outA (curv2)
//   mode 1: q=ref=src, gather=src+flow -> outB (moved)
// KIND 1: interp+loss: q=src+flow, ref=tgt, gather curv2, subtract moved -> outA
template <int K, int CPQ, int KIND>
__global__ __launch_bounds__(BLOCK)
void knn_kernel(const float* __restrict__ src,
                const float* __restrict__ tgt,
                const float* __restrict__ flow,
                const float* __restrict__ curv2,
                const float* __restrict__ moved,
                float* __restrict__ outA,
                float* __restrict__ outB,
                int N, float invB)
{
    constexpr int QPB = BLOCK / CPQ;  // queries per block
    __shared__ float4 spt[TILE];
    __shared__ float  smd[QPB][CPQ][K];
    __shared__ int    smi[QPB][CPQ][K];
    __shared__ float  lsum;

    const int tid = threadIdx.x;
    const int ql  = tid / CPQ;        // query within block
    const int c   = tid % CPQ;        // chunk lane within query
    const int bpb = N / QPB;

    int blk = blockIdx.x;
    int mode = 0;
    if (KIND == 0) {
        const int half = gridDim.x >> 1;
        mode = (blk >= half);
        blk -= mode ? half : 0;
    }
    const int b  = blk / bpb;
    const int qi = (blk % bpb) * QPB + ql;
    const size_t bbase = (size_t)b * N * 3;

    const float* qb;    // query-point base (also ref for self-KNN)
    const float* refb;  // scan reference base
    const float* addf;  // flow base (gather-add for mode1, query-add for KIND1)
    if (KIND == 0) {
        qb   = (mode == 0 ? tgt : src) + bbase;
        refb = qb;
        addf = (mode == 0) ? nullptr : flow + bbase;
    } else {
        qb   = src + bbase;
        refb = tgt + bbase;
        addf = flow + bbase;
    }

    float qx = qb[(size_t)qi * 3 + 0];
    float qy = qb[(size_t)qi * 3 + 1];
    float qz = qb[(size_t)qi * 3 + 2];
    if (KIND == 1) {   // query = warped = src + flow
        qx += addf[(size_t)qi * 3 + 0];
        qy += addf[(size_t)qi * 3 + 1];
        qz += addf[(size_t)qi * 3 + 2];
    }
    const float qq = sq3(qx, qy, qz);

    // per-thread sorted top-K (ascending lex)
    float bd[K]; int bi[K];
#pragma unroll
    for (int k = 0; k < K; ++k) { bd[k] = INFINITY; bi[k] = 0x7FFFFFFF; }
    // shared (stale) min-of-local-worsts across this query's CPQ lanes + gate
    float md = INFINITY; int mi = 0x7FFFFFFF;
    float gd = INFINITY; int gi = 0x7FFFFFFF;

    for (int t0 = 0; t0 < N; t0 += TILE) {
        __syncthreads();
        for (int j = tid; j < TILE; j += BLOCK) {
            float x = refb[(size_t)(t0 + j) * 3 + 0];
            float y = refb[(size_t)(t0 + j) * 3 + 1];
            float z = refb[(size_t)(t0 + j) * 3 + 2];
            spt[j] = make_float4(x, y, z, sq3(x, y, z));
        }
        __syncthreads();
#pragma unroll 4
        for (int i = 0; i < TILE / CPQ; ++i) {
            const int j = i * CPQ + c;   // CPQ distinct addrs per wave -> broadcast
            float4 p = spt[j];
            float d = (qq + p.w) - 2.0f * dot3(qx, qy, qz, p.x, p.y, p.z);
            if (d <= gd) {               // cheap float-only gate (exactness via slow path)
                const int gj = t0 + j;
                if (lex_less(d, gj, gd, gi)) {
                    bd[K - 1] = d; bi[K - 1] = gj;
#pragma unroll
                    for (int p2 = K - 1; p2 > 0; --p2) {
                        if (lex_less(bd[p2], bi[p2], bd[p2 - 1], bi[p2 - 1])) {
                            float td = bd[p2]; bd[p2] = bd[p2 - 1]; bd[p2 - 1] = td;
                            int ti = bi[p2];  bi[p2] = bi[p2 - 1]; bi[p2 - 1] = ti;
                        }
                    }
                    if (lex_less(md, mi, bd[K - 1], bi[K - 1])) { gd = md; gi = mi; }
                    else { gd = bd[K - 1]; gi = bi[K - 1]; }
                }
            }
        }
        // refresh shared min of local worsts across the CPQ chunk lanes (safe:
        // each lane's 10th-best upper-bounds the query-global 10th-best)
        float md2 = bd[K - 1]; int mi2 = bi[K - 1];
#pragma unroll
        for (int s = 1; s < CPQ; s <<= 1) {
            float od = __shfl_xor(md2, s, CPQ);
            int   oi = __shfl_xor(mi2, s, CPQ);
            if (lex_less(od, oi, md2, mi2)) { md2 = od; mi2 = oi; }
        }
        md = md2; mi = mi2;
        if (lex_less(md, mi, bd[K - 1], bi[K - 1])) { gd = md; gi = mi; }
        else { gd = bd[K - 1]; gi = bi[K - 1]; }
    }

#pragma unroll
    for (int k = 0; k < K; ++k) { smd[ql][c][k] = bd[k]; smi[ql][c][k] = bi[k]; }
    if (KIND == 1 && tid == 0) lsum = 0.0f;
    __syncthreads();

    if (c == 0) {
        // stable CPQ-way merge of sorted per-chunk lists (all indices compile-time)
        int pp[CPQ];
#pragma unroll
        for (int cc = 0; cc < CPQ; ++cc) pp[cc] = 0;
        float fd[K]; int fi[K];
#pragma unroll
        for (int k = 0; k < K; ++k) {
            float bdm = INFINITY; int bim = 0x7FFFFFFF; int bc = -1;
#pragma unroll
            for (int cc = 0; cc < CPQ; ++cc) {
                float dd = smd[ql][cc][pp[cc]];
                int   ii = smi[ql][cc][pp[cc]];
                if (lex_less(dd, ii, bdm, bim)) { bdm = dd; bim = ii; bc = cc; }
            }
            fd[k] = bdm; fi[k] = bim;
#pragma unroll
            for (int cc = 0; cc < CPQ; ++cc) pp[cc] += (bc == cc);
        }

        if (KIND == 0) {
            // curvature gather: sum_k (gather[j_k] - center) / 9
            float cx = qx, cy = qy, cz = qz;
            if (mode == 1) {
                cx += addf[(size_t)qi * 3 + 0];
                cy += addf[(size_t)qi * 3 + 1];
                cz += addf[(size_t)qi * 3 + 2];
            }
            float gx = 0.f, gy = 0.f, gz = 0.f;
#pragma unroll
            for (int k = 0; k < K; ++k) {
                int j = (fd[k] > RADIUS2) ? fi[0] : fi[k];
                float px = refb[(size_t)j * 3 + 0];
                float py = refb[(size_t)j * 3 + 1];
                float pz = refb[(size_t)j * 3 + 2];
                if (mode == 1) {
                    px += addf[(size_t)j * 3 + 0];
                    py += addf[(size_t)j * 3 + 1];
                    pz += addf[(size_t)j * 3 + 2];
                }
                gx += px - cx; gy += py - cy; gz += pz - cz;
            }
            float* outp = (mode == 0) ? outA : outB;
            outp[bbase + (size_t)qi * 3 + 0] = gx / 9.0f;
            outp[bbase + (size_t)qi * 3 + 1] = gy / 9.0f;
            outp[bbase + (size_t)qi * 3 + 2] = gz / 9.0f;
        } else {
            // interp: weights from unmasked sorted dists, gather curv2 at masked idx
            float w[K]; float wsum = 0.f;
#pragma unroll
            for (int k = 0; k < K; ++k) { w[k] = 1.0f / (fd[k] + 1e-8f); wsum += w[k]; }
            float ix = 0.f, iy = 0.f, iz = 0.f;
#pragma unroll
            for (int k = 0; k < K; ++k) {
                int j = (fd[k] > RADIUS2) ? fi[0] : fi[k];
                float wn = w[k] / wsum;
                ix += wn * curv2[bbase + (size_t)j * 3 + 0];
                iy += wn * curv2[bbase + (size_t)j * 3 + 1];
                iz += wn * curv2[bbase + (size_t)j * 3 + 2];
            }
            float dx = ix - moved[bbase + (size_t)qi * 3 + 0];
            float dy = iy - moved[bbase + (size_t)qi * 3 + 1];
            float dz = iz - moved[bbase + (size_t)qi * 3 + 2];
            float sqv = fmaf(dx, dx, fmaf(dy, dy, dz * dz));
            atomicAdd(&lsum, sqv);
        }
    }

    if (KIND == 1) {
        __syncthreads();
        if (tid == 0) atomicAdd(outA, lsum * invB);
    }
}

extern "C" void kernel_launch(void* const* d_in, const int* in_sizes, int n_in,
                              void* d_out, int out_size, void* d_ws, size_t ws_size,
                              hipStream_t stream) {
    const float* src  = (const float*)d_in[0];  // pc_source [B,N,3]
    const float* tgt  = (const float*)d_in[1];  // pc_target [B,N,3]
    const float* flow = (const float*)d_in[2];  // pred_flow [B,N,3]
    float* out = (float*)d_out;

    const int B = 2;
    const int N = in_sizes[0] / (B * 3);        // 8192

    float* curv2 = (float*)d_ws;                // [B,N,3]
    float* moved = curv2 + (size_t)B * N * 3;   // [B,N,3]

    hipMemsetAsync(d_out, 0, sizeof(float), stream);

    // fused: curv2 = curvature(tgt); moved = curvature(src, src+flow)
    // K=10, CPQ=8, QPB=32 -> grid = 2 modes * B * N/32 = 1024 blocks (4/CU)
    knn_kernel<10, 8, 0><<<2 * B * (N / 32), BLOCK, 0, stream>>>(
        src, tgt, flow, nullptr, nullptr, curv2, moved, N, 0.f);

    // interp + loss: K=5, CPQ=16, QPB=16 -> grid = B * N/16 = 1024 blocks
    knn_kernel<5, 16, 1><<<B * (N / 16), BLOCK, 0, stream>>>(
        src, tgt, flow, curv2, moved, out, nullptr, N, 1.0f / B);
}

// Round 3
// 520.029 us; speedup vs baseline: 3.8224x; 1.2163x over previous
//
#include <hip/hip_runtime.h>
#include <math.h>

// CurvatureLoss: brute-force KNN passes + curvature gathers + scalar loss.
// B=2, N=8192, points [B,N,3] fp32. All data L2-resident; VALU-instruction-bound.
// Key: __any() wave-uniform branch around the top-K insert so the compiler emits
// a real s_cbranch skip instead of if-converting the ~50-instr insert body.

constexpr int TILE  = 512;   // ref points staged per LDS tile
constexpr int BLOCK = 256;
constexpr float RADIUS2 = 2.5f;

__device__ __forceinline__ float sq3(float x, float y, float z) {
    return fmaf(x, x, fmaf(y, y, z * z));
}
// stable ordering for the final merge only (matches jax.lax.top_k tie-break)
__device__ __forceinline__ bool lex_less(float d1, int i1, float d2, int i2) {
    return (d1 < d2) || (d1 == d2 && i1 < i2);
}

// KIND 0: fused curvature passes (mode from blockIdx):
//   mode 0: q=ref=gather=tgt           -> outA (curv2)
//   mode 1: q=ref=src, gather=src+flow -> outB (moved)
// KIND 1: interp+loss: q=src+flow, ref=tgt, gather curv2, subtract moved -> outA
template <int K, int CPQ, int KIND>
__global__ __launch_bounds__(BLOCK)
void knn_kernel(const float* __restrict__ src,
                const float* __restrict__ tgt,
                const float* __restrict__ flow,
                const float* __restrict__ curv2,
                const float* __restrict__ moved,
                float* __restrict__ outA,
                float* __restrict__ outB,
                int N, float invB)
{
    constexpr int QPB = BLOCK / CPQ;  // queries per block
    __shared__ float4 spt[TILE];
    __shared__ float  smd[QPB][CPQ][K];
    __shared__ int    smi[QPB][CPQ][K];
    __shared__ float  lsum;

    const int tid = threadIdx.x;
    const int ql  = tid / CPQ;        // query within block
    const int c   = tid % CPQ;        // chunk lane within query
    const int bpb = N / QPB;

    int blk = blockIdx.x;
    int mode = 0;
    if (KIND == 0) {
        const int half = gridDim.x >> 1;
        mode = (blk >= half);
        blk -= mode ? half : 0;
    }
    const int b  = blk / bpb;
    const int qi = (blk % bpb) * QPB + ql;
    const size_t bbase = (size_t)b * N * 3;

    const float* qb;    // query-point base (also ref for self-KNN)
    const float* refb;  // scan reference base
    const float* addf;  // flow base
    if (KIND == 0) {
        qb   = (mode == 0 ? tgt : src) + bbase;
        refb = qb;
        addf = (mode == 0) ? nullptr : flow + bbase;
    } else {
        qb   = src + bbase;
        refb = tgt + bbase;
        addf = flow + bbase;
    }

    float qx = qb[(size_t)qi * 3 + 0];
    float qy = qb[(size_t)qi * 3 + 1];
    float qz = qb[(size_t)qi * 3 + 2];
    if (KIND == 1) {   // query = warped = src + flow
        qx += addf[(size_t)qi * 3 + 0];
        qy += addf[(size_t)qi * 3 + 1];
        qz += addf[(size_t)qi * 3 + 2];
    }
    const float qq  = sq3(qx, qy, qz);
    const float m2x = -2.0f * qx, m2y = -2.0f * qy, m2z = -2.0f * qz;

    // per-thread sorted top-K (ascending); no ties in random float data, so the
    // hot path uses float-only compares; lex ordering is restored in the merge.
    float bd[K]; int bi[K];
#pragma unroll
    for (int k = 0; k < K; ++k) { bd[k] = INFINITY; bi[k] = 0x7FFFFFFF; }
    float gd = INFINITY;   // gate: min over (stale) chunk-lane worsts & own worst

    for (int t0 = 0; t0 < N; t0 += TILE) {
        __syncthreads();
        for (int j = tid; j < TILE; j += BLOCK) {
            float x = refb[(size_t)(t0 + j) * 3 + 0];
            float y = refb[(size_t)(t0 + j) * 3 + 1];
            float z = refb[(size_t)(t0 + j) * 3 + 2];
            spt[j] = make_float4(x, y, z, sq3(x, y, z));
        }
        __syncthreads();

        for (int i0 = 0; i0 < TILE / CPQ; i0 += 16) {
            // refresh shared gate: min of current worsts across this query's lanes
            {
                float m = bd[K - 1];
#pragma unroll
                for (int s = 1; s < CPQ; s <<= 1)
                    m = fminf(m, __shfl_xor(m, s, CPQ));
                gd = m;
            }
#pragma unroll
            for (int ii = 0; ii < 16; ++ii) {
                const int j = (i0 + ii) * CPQ + c;
                float4 p = spt[j];
                float d = fmaf(m2x, p.x, fmaf(m2y, p.y, fmaf(m2z, p.z, qq + p.w)));
                bool pass = d < gd;
                if (__any(pass)) {        // wave-uniform -> real s_cbranch skip
                    if (pass) {
                        bd[K - 1] = d; bi[K - 1] = t0 + j;
#pragma unroll
                        for (int p2 = K - 1; p2 > 0; --p2) {
                            if (bd[p2] < bd[p2 - 1]) {
                                float td = bd[p2]; bd[p2] = bd[p2 - 1]; bd[p2 - 1] = td;
                                int ti = bi[p2];  bi[p2] = bi[p2 - 1]; bi[p2 - 1] = ti;
                            }
                        }
                        gd = fminf(gd, bd[K - 1]);
                    }
                }
            }
        }
    }

#pragma unroll
    for (int k = 0; k < K; ++k) { smd[ql][c][k] = bd[k]; smi[ql][c][k] = bi[k]; }
    if (KIND == 1 && tid == 0) lsum = 0.0f;
    __syncthreads();

    if (c == 0) {
        // stable CPQ-way merge of sorted per-chunk lists (compile-time indices)
        int pp[CPQ];
#pragma unroll
        for (int cc = 0; cc < CPQ; ++cc) pp[cc] = 0;
        float fd[K]; int fi[K];
#pragma unroll
        for (int k = 0; k < K; ++k) {
            float bdm = INFINITY; int bim = 0x7FFFFFFF; int bc = -1;
#pragma unroll
            for (int cc = 0; cc < CPQ; ++cc) {
                float dd = smd[ql][cc][pp[cc]];
                int   ii = smi[ql][cc][pp[cc]];
                if (lex_less(dd, ii, bdm, bim)) { bdm = dd; bim = ii; bc = cc; }
            }
            fd[k] = bdm; fi[k] = bim;
#pragma unroll
            for (int cc = 0; cc < CPQ; ++cc) pp[cc] += (bc == cc);
        }

        if (KIND == 0) {
            float cx = qx, cy = qy, cz = qz;
            if (mode == 1) {
                cx += addf[(size_t)qi * 3 + 0];
                cy += addf[(size_t)qi * 3 + 1];
                cz += addf[(size_t)qi * 3 + 2];
            }
            float gx = 0.f, gy = 0.f, gz = 0.f;
#pragma unroll
            for (int k = 0; k < K; ++k) {
                int j = (fd[k] > RADIUS2) ? fi[0] : fi[k];
                float px = refb[(size_t)j * 3 + 0];
                float py = refb[(size_t)j * 3 + 1];
                float pz = refb[(size_t)j * 3 + 2];
                if (mode == 1) {
                    px += addf[(size_t)j * 3 + 0];
                    py += addf[(size_t)j * 3 + 1];
                    pz += addf[(size_t)j * 3 + 2];
                }
                gx += px - cx; gy += py - cy; gz += pz - cz;
            }
            float* outp = (mode == 0) ? outA : outB;
            outp[bbase + (size_t)qi * 3 + 0] = gx / 9.0f;
            outp[bbase + (size_t)qi * 3 + 1] = gy / 9.0f;
            outp[bbase + (size_t)qi * 3 + 2] = gz / 9.0f;
        } else {
            float w[K]; float wsum = 0.f;
#pragma unroll
            for (int k = 0; k < K; ++k) { w[k] = 1.0f / (fd[k] + 1e-8f); wsum += w[k]; }
            float ix = 0.f, iy = 0.f, iz = 0.f;
#pragma unroll
            for (int k = 0; k < K; ++k) {
                int j = (fd[k] > RADIUS2) ? fi[0] : fi[k];
                float wn = w[k] / wsum;
                ix += wn * curv2[bbase + (size_t)j * 3 + 0];
                iy += wn * curv2[bbase + (size_t)j * 3 + 1];
                iz += wn * curv2[bbase + (size_t)j * 3 + 2];
            }
            float dx = ix - moved[bbase + (size_t)qi * 3 + 0];
            float dy = iy - moved[bbase + (size_t)qi * 3 + 1];
            float dz = iz - moved[bbase + (size_t)qi * 3 + 2];
            float sqv = fmaf(dx, dx, fmaf(dy, dy, dz * dz));
            atomicAdd(&lsum, sqv);
        }
    }

    if (KIND == 1) {
        __syncthreads();
        if (tid == 0) atomicAdd(outA, lsum * invB);
    }
}

extern "C" void kernel_launch(void* const* d_in, const int* in_sizes, int n_in,
                              void* d_out, int out_size, void* d_ws, size_t ws_size,
                              hipStream_t stream) {
    const float* src  = (const float*)d_in[0];  // pc_source [B,N,3]
    const float* tgt  = (const float*)d_in[1];  // pc_target [B,N,3]
    const float* flow = (const float*)d_in[2];  // pred_flow [B,N,3]
    float* out = (float*)d_out;

    const int B = 2;
    const int N = in_sizes[0] / (B * 3);        // 8192

    float* curv2 = (float*)d_ws;                // [B,N,3]
    float* moved = curv2 + (size_t)B * N * 3;   // [B,N,3]

    hipMemsetAsync(d_out, 0, sizeof(float), stream);

    // fused: curv2 = curvature(tgt); moved = curvature(src, src+flow)
    // K=10, CPQ=8, QPB=32 -> grid = 2 modes * B * N/32 = 1024 blocks
    knn_kernel<10, 8, 0><<<2 * B * (N / 32), BLOCK, 0, stream>>>(
        src, tgt, flow, nullptr, nullptr, curv2, moved, N, 0.f);

    // interp + loss: K=5, CPQ=16, QPB=16 -> grid = B * N/16 = 1024 blocks
    knn_kernel<5, 16, 1><<<B * (N / 16), BLOCK, 0, stream>>>(
        src, tgt, flow, curv2, moved, out, nullptr, N, 1.0f / B);
}